// Round 14
// baseline (371.515 us; speedup 1.0000x reference)
//
#include <hip/hip_runtime.h>
#include <math.h>
#include <limits.h>

#define N_SAMPLES 65536
#define N_FRAMES  128
#define NUM_COEFF 6
#define NSEG      126        // N_FRAMES - 2
#define VEC_SIZE  808
#define ZCLAMP    (VEC_SIZE - 7)   // 801
#define NBLOCKS   320

// ---- workspace layout (byte offsets) ----
#define WS_XL    0           // float xl[65536]
#define WS_PP    262144      // float PP[65536]
#define WS_VALS  524288      // float vals8[65536][8]; slot 7 = z (float)
#define WS_TM    2621440     // float TM[64]
#define WS_TC    2621696     // float TC[64]
#define WS_D     2621952     // int: min dependency distance
#define WS_BAR   2622208     // int[2]: grid-barrier {cnt, gen} (memset to 0)
#define WS_PL    2622464     // 3 SoA planes: float4[65536] each
#define WS_MQ    5768192     // float4[65536] = (X15, ring_idx_f, u12, u13)

// bf16 RNE pack helpers
__device__ __forceinline__ unsigned int bf16_hi(float f) {
    unsigned int b = __float_as_uint(f);
    b = b + 0x7fffu + ((b >> 16) & 1u);
    return b & 0xffff0000u;
}
__device__ __forceinline__ unsigned int bf16_lo(float f) {
    unsigned int b = __float_as_uint(f);
    b = b + 0x7fffu + ((b >> 16) & 1u);
    return b >> 16;
}

// lgkm-only workgroup barrier (global loads/stores stay in flight)
__device__ __forceinline__ void bar_lgkm() {
    asm volatile("s_waitcnt lgkmcnt(0)\n\ts_barrier" ::: "memory");
}

// Sense-reversing grid barrier (device scope). All NBLOCKS blocks are
// co-resident (LDS 42 KB -> 3 blocks/CU -> 768 slots >= 320), so spinning
// is deadlock-free. cnt reset happens before gen bump (release-ordered), so
// a racing fast block cannot corrupt the next round's count.
__device__ __forceinline__ void grid_barrier(int* bar) {
    __syncthreads();
    if (threadIdx.x == 0) {
        __threadfence();
        int* cnt = bar;
        int* gen = bar + 1;
        const int g = __hip_atomic_load(gen, __ATOMIC_ACQUIRE, __HIP_MEMORY_SCOPE_AGENT);
        const int prev = __hip_atomic_fetch_add(cnt, 1, __ATOMIC_ACQ_REL, __HIP_MEMORY_SCOPE_AGENT);
        if (prev == NBLOCKS - 1) {
            __hip_atomic_store(cnt, 0, __ATOMIC_RELEASE, __HIP_MEMORY_SCOPE_AGENT);
            __hip_atomic_fetch_add(gen, 1, __ATOMIC_ACQ_REL, __HIP_MEMORY_SCOPE_AGENT);
        } else {
            while (__hip_atomic_load(gen, __ATOMIC_ACQUIRE, __HIP_MEMORY_SCOPE_AGENT) == g) {
                __builtin_amdgcn_s_sleep(1);
            }
        }
        __threadfence();
    }
    __syncthreads();
}

// ---------------------------------------------------------------------------
// Single fused kernel: phase 1 (front-end) -> grid barrier ->
// phase 2 (expansion) -> grid barrier -> phase 3 (block 0: recurrence).
// Phase bodies are verbatim ports of the R13-verified kernels.
// ---------------------------------------------------------------------------
__global__ __launch_bounds__(256, 1) void k_all(
    const float* __restrict__ delay_len,
    const float* __restrict__ raw_gain,
    const float* __restrict__ raw_coeff,
    const float* __restrict__ exc,
    const float* __restrict__ burst,
    float* __restrict__ ws,
    float* __restrict__ out)
{
    __shared__ __align__(16) union {
        struct { float Y[7][N_FRAMES]; float M[7][N_FRAMES];
                 double cp[NSEG]; double dp[7][NSEG]; } sp;
        struct { float sm[256], sc[256]; } ex;
        struct { float accL[256 * 33]; float xwin[1920];
                 float yin[64]; int dmin; } xp;
        struct { float ring2[4096]; } ks;
    } u;

    const int tid = threadIdx.x;
    const int b = blockIdx.x;
    int* bar = (int*)((char*)ws + WS_BAR);

    // ======================= PHASE 1: front-end =======================
    if (b >= 256) {
        // exc IIR phase-1, tile = b - 256
        float* xl = ws + WS_XL / 4;
        float* PP = ws + WS_PP / 4;
        float* TM = ws + WS_TM / 4;
        float* TC = ws + WS_TC / 4;
        const int tile = b - 256;
        const int base = tile * 1024 + tid * 4;

        if (tile == 0 && tid == 0) *(int*)((char*)ws + WS_D) = 0x7fffffff;

        const float4 a4 = *(const float4*)(exc + base);
        const float4 b4 = *(const float4*)(burst + base);

        float m = -a4.x,            c = b4.x;
        m = -a4.y * m;              c = b4.y - a4.y * c;
        m = -a4.z * m;              c = b4.z - a4.z * c;
        m = -a4.w * m;              c = b4.w - a4.w * c;

        u.ex.sm[tid] = m; u.ex.sc[tid] = c;
        __syncthreads();
        for (int off = 1; off < 256; off <<= 1) {
            const float cm = u.ex.sm[tid], cc = u.ex.sc[tid];
            float pm = 1.f, pc = 0.f;
            if (tid >= off) { pm = u.ex.sm[tid - off]; pc = u.ex.sc[tid - off]; }
            __syncthreads();
            if (tid >= off) { u.ex.sm[tid] = cm * pm; u.ex.sc[tid] = cm * pc + cc; }
            __syncthreads();
        }
        float y = (tid == 0) ? 0.f : u.ex.sc[tid - 1];
        float P = (tid == 0) ? 1.f : u.ex.sm[tid - 1];

        float4 x4, p4;
        y = b4.x - a4.x * y;  P = -a4.x * P;  x4.x = y; p4.x = P;
        y = b4.y - a4.y * y;  P = -a4.y * P;  x4.y = y; p4.y = P;
        y = b4.z - a4.z * y;  P = -a4.z * P;  x4.z = y; p4.z = P;
        y = b4.w - a4.w * y;  P = -a4.w * P;  x4.w = y; p4.w = P;

        *(float4*)(xl + base) = x4;
        *(float4*)(PP + base) = p4;
        if (tid == 255) { TM[tile] = u.ex.sm[255]; TC[tile] = u.ex.sc[255]; }
    } else {
        // spline path
        float* vals8 = ws + WS_VALS / 4;

        if (tid < N_FRAMES) {
            float s[NUM_COEFF];
            float sum = 0.f;
            for (int j = 0; j < NUM_COEFF; ++j) {
                s[j] = 1.f / (1.f + expf(-raw_coeff[tid * NUM_COEFF + j]));
                sum += s[j];
            }
            const float gain = 1.f / (1.f + expf(-raw_gain[0]));
            for (int j = 0; j < NUM_COEFF; ++j)
                u.sp.Y[1 + j][tid] = s[j] / sum * gain;
            u.sp.Y[0][tid] = delay_len[tid];
        }
        __syncthreads();

        if (tid == 0) {
            u.sp.cp[0] = 0.25;
            for (int i = 1; i < NSEG; ++i) u.sp.cp[i] = 1.0 / (4.0 - u.sp.cp[i - 1]);
        }
        __syncthreads();

        if (tid < 7) {
            const float* y = u.sp.Y[tid];
            const double inv_h2 = 127.0 * 127.0;
            double prev = 6.0 * ((double)y[2] - 2.0 * (double)y[1] + (double)y[0]) * inv_h2 * 0.25;
            u.sp.dp[tid][0] = prev;
            for (int i = 1; i < NSEG; ++i) {
                double ri = 6.0 * ((double)y[i + 2] - 2.0 * (double)y[i + 1] + (double)y[i]) * inv_h2;
                prev = (ri - prev) * u.sp.cp[i];
                u.sp.dp[tid][i] = prev;
            }
            float* Mc = u.sp.M[tid];
            Mc[0] = 0.f; Mc[N_FRAMES - 1] = 0.f;
            double mi = u.sp.dp[tid][NSEG - 1];
            Mc[NSEG] = (float)mi;
            for (int i = NSEG - 2; i >= 0; --i) {
                mi = u.sp.dp[tid][i] - u.sp.cp[i] * mi;
                Mc[i + 1] = (float)mi;
            }
        }
        __syncthreads();

        const int t = b * 256 + tid;
        const float h = 1.0f / 127.0f;
        const float tf = (float)t * (1.0f / 65535.0f);
        int idx = (int)floorf(tf * 127.0f);
        idx = min(max(idx, 0), 126);
        const float s = tf - (float)idx * h;
        const float s2 = s * s;
        const float s3 = s2 * s;

        float o[7];
#pragma unroll
        for (int c = 0; c < 7; ++c) {
            const float yi  = u.sp.Y[c][idx];
            const float yi1 = u.sp.Y[c][idx + 1];
            const float Mi  = u.sp.M[c][idx];
            const float Mi1 = u.sp.M[c][idx + 1];
            const float bb = (yi1 - yi) / h - h * (2.f * Mi + Mi1) / 6.f;
            o[c] = yi + bb * s + 0.5f * Mi * s2 + (Mi1 - Mi) * s3 / (6.f * h);
        }
        const float delay = o[0];
        int z = (int)floorf(delay);
        const float alfa = delay - (float)z;
        z = min(max(z, 0), ZCLAMP);

        float v[8];
        v[0] = -((1.f - alfa) * o[1]);
#pragma unroll
        for (int j = 1; j <= 5; ++j)
            v[j] = -(alfa * o[j] + (1.f - alfa) * o[j + 1]);
        v[6] = -(alfa * o[6]);
        v[7] = (float)z;

        float4* vp = (float4*)(vals8 + (size_t)t * 8);
        vp[0] = make_float4(v[0], v[1], v[2], v[3]);
        vp[1] = make_float4(v[4], v[5], v[6], v[7]);
    }

    grid_barrier(bar);

    // ======================= PHASE 2: expansion =======================
    if (b < 256) {
        const int T0 = b * 256;
        const int t = T0 + tid;
        const int wlo = T0 - 1664;

        const float* xl = ws + WS_XL / 4;
        const float* PP = ws + WS_PP / 4;
        const float* vals8 = ws + WS_VALS / 4;
        const float* TM = ws + WS_TM / 4;
        const float* TC = ws + WS_TC / 4;
        float4* PL = (float4*)((char*)ws + WS_PL);
        float4* MQ = (float4*)((char*)ws + WS_MQ);
        int* D = (int*)((char*)ws + WS_D);

        float* acc = u.xp.accL + tid * 33;
#pragma unroll
        for (int o = 0; o < 32; ++o) acc[o] = 0.f;

        if (tid == 0) {
            u.xp.dmin = 0x7fffffff;
            float y = 0.f;
            for (int k = 0; k < 64; ++k) {
                u.xp.yin[k] = y;
                y = TC[k] + TM[k] * y;
            }
        }
        __syncthreads();

        for (int i = tid; i < 1920; i += 256) {
            const int p = wlo + i;
            float xv = 0.f;
            if (p >= 0 && p < N_SAMPLES)
                xv = xl[p] + PP[p] * u.xp.yin[p >> 10];
            u.xp.xwin[i] = xv;
        }
        __syncthreads();

#define XREAD(p) u.xp.xwin[(p) - wlo]

        const float4* vp = (const float4*)(vals8 + (size_t)t * 8);
        const float4 r0 = vp[0], r1 = vp[1];
        const float vj[7] = {r0.x, r0.y, r0.z, r0.w, r1.x, r1.y, r1.z};
        const int m0 = t - 1 - (int)r1.w;
        float X1 = XREAD(t);

        float4 s0[7], s1[7];
        float xs[7];
        int sm0[7];
        bool val[7];
        int pmin = INT_MAX;
#pragma unroll
        for (int j = 0; j < 7; ++j) {
            const int s = m0 - j;
            val[j] = (s >= 0);
            const int si = val[j] ? s : 0;
            const float4* sp = (const float4*)(vals8 + (size_t)si * 8);
            s0[j] = sp[0]; s1[j] = sp[1];
            xs[j] = XREAD(val[j] ? s : t);
            sm0[j] = s - 1 - (int)s1[j].w;
            if (val[j]) pmin = min(pmin, sm0[j]);
        }
        if (pmin == INT_MAX) pmin = t - 900;
        const int B1 = (pmin - 6) & ~3;

#pragma unroll
        for (int j = 0; j < 7; ++j) {
            if (!val[j]) continue;
            X1 -= vj[j] * xs[j];
            const float sv[7] = {s0[j].x, s0[j].y, s0[j].z, s0[j].w,
                                 s1[j].x, s1[j].y, s1[j].z};
            const int ob = sm0[j] - B1;
#pragma unroll
            for (int k = 0; k < 7; ++k) {
                int o = ob - k;
                o = min(max(o, 0), 31);
                acc[o] += vj[j] * sv[k];
            }
        }

        float c1f[32];
#pragma unroll
        for (int o = 0; o < 32; ++o) { c1f[o] = acc[o]; acc[o] = 0.f; }

        float X15 = X1;
        int first = -1;
#pragma unroll
        for (int o = 0; o < 32; ++o)
            if (first < 0 && c1f[o] != 0.f && (B1 + o) >= 0) first = o;

        int B2 = 0, maxq = INT_MIN;
        if (first >= 0) {
            const int pf = B1 + first;
            const float zf = ((const float4*)(vals8 + (size_t)pf * 8))[1].w;
            B2 = ((pf - 1 - (int)zf) - 6) & ~3;

#pragma unroll
            for (int o = 0; o < 32; ++o) {
                const float co = c1f[o];
                const int p = B1 + o;
                if (co == 0.f || p < 0) continue;
                const float4* pv = (const float4*)(vals8 + (size_t)p * 8);
                const float4 v0 = pv[0], v1 = pv[1];
                X15 += co * XREAD(p);
                const int rp = p - 1 - (int)v1.w;
                maxq = max(maxq, rp);
                const float sv[7] = {v0.x, v0.y, v0.z, v0.w, v1.x, v1.y, v1.z};
                const int ob = rp - B2;
#pragma unroll
                for (int j = 0; j < 7; ++j) {
                    int oo = ob - j;
                    oo = min(max(oo, 0), 27);   // band fits in [0,27]
                    acc[oo] -= co * sv[j];
                }
            }
        }
#undef XREAD

        unsigned int uu[14];
#pragma unroll
        for (int i = 0; i < 14; ++i)
            uu[i] = bf16_hi(acc[2 * i]) | bf16_lo(acc[2 * i + 1]);

        PL[t]             = make_float4(__uint_as_float(uu[0]),  __uint_as_float(uu[1]),
                                        __uint_as_float(uu[2]),  __uint_as_float(uu[3]));
        PL[t + 65536]     = make_float4(__uint_as_float(uu[4]),  __uint_as_float(uu[5]),
                                        __uint_as_float(uu[6]),  __uint_as_float(uu[7]));
        PL[t + 2 * 65536] = make_float4(__uint_as_float(uu[8]),  __uint_as_float(uu[9]),
                                        __uint_as_float(uu[10]), __uint_as_float(uu[11]));
        MQ[t] = make_float4(X15, (float)(B2 & 2047),
                            __uint_as_float(uu[12]), __uint_as_float(uu[13]));

        if (first >= 0 && maxq > INT_MIN) atomicMin(&u.xp.dmin, t - maxq);
        __syncthreads();
        if (tid == 0) atomicMin(D, u.xp.dmin);
    }

    grid_barrier(bar);

    // ======================= PHASE 3: recurrence (block 0) =============
    if (b != 0) return;

    {
        float* ring2 = u.ks.ring2;
        const float4* PL = (const float4*)((const char*)ws + WS_PL);
        const float4* MQ = (const float4*)((const char*)ws + WS_MQ);
        const int* Dp = (const int*)((const char*)ws + WS_D);

        for (int i = tid; i < 4096; i += 256) ring2[i] = 0.f;
        __syncthreads();

        int C = *Dp;
        if (C > 256) C = 256;
        if (C < 1) C = 1;
        const int C2 = 2 * C;
        const bool act = (tid < C);

        float4 A0, A1, A2, AM;
        float4 B0, B1, B2, BM;

#define PRE(P0, P1, P2, PM, BASE)                                              \
    do {                                                                       \
        int tL = (BASE) + tid;                                                 \
        if (tL > N_SAMPLES - 1) tL = N_SAMPLES - 1;                            \
        P0 = PL[tL];  P1 = PL[tL + 65536];  P2 = PL[tL + 2 * 65536];           \
        PM = MQ[tL];                                                           \
    } while (0)

#define STEP(P0, P1, P2, PM, S_)                                               \
    do {                                                                       \
        const int t0 = (S_) + tid;                                             \
        if (act && t0 < N_SAMPLES) {                                           \
            const int idx_ = (int)(PM).y;                                      \
            const unsigned int hi_ = 0xffff0000u;                              \
            const unsigned int u_[14] = {                                      \
                __float_as_uint((P0).x), __float_as_uint((P0).y),              \
                __float_as_uint((P0).z), __float_as_uint((P0).w),              \
                __float_as_uint((P1).x), __float_as_uint((P1).y),              \
                __float_as_uint((P1).z), __float_as_uint((P1).w),              \
                __float_as_uint((P2).x), __float_as_uint((P2).y),              \
                __float_as_uint((P2).z), __float_as_uint((P2).w),              \
                __float_as_uint((PM).z), __float_as_uint((PM).w)};             \
            float p0 = 0.f, p1 = 0.f, p2 = 0.f, p3 = 0.f;                      \
            _Pragma("unroll")                                                  \
            for (int q = 0; q < 7; ++q) {                                      \
                const float4 rv_ = *(const float4*)&ring2[idx_ + 4 * q];       \
                const unsigned int ua_ = u_[2 * q], ub_ = u_[2 * q + 1];       \
                p0 = fmaf(__uint_as_float(ua_ & hi_), rv_.x, p0);              \
                p1 = fmaf(__uint_as_float(ua_ << 16), rv_.y, p1);              \
                p2 = fmaf(__uint_as_float(ub_ & hi_), rv_.z, p2);              \
                p3 = fmaf(__uint_as_float(ub_ << 16), rv_.w, p3);              \
            }                                                                  \
            const float y_ = (PM).x + ((p0 + p1) + (p2 + p3));                 \
            const int w_ = t0 & 2047;                                          \
            ring2[w_] = y_; ring2[w_ + 2048] = y_; out[t0] = y_;               \
        }                                                                      \
        PRE(P0, P1, P2, PM, (S_) + C2);                                        \
        bar_lgkm();                                                            \
    } while (0)

        PRE(A0, A1, A2, AM, 0);
        PRE(B0, B1, B2, BM, C);
        for (int S = 0; S < N_SAMPLES; S += C2) {
            STEP(A0, A1, A2, AM, S);
            STEP(B0, B1, B2, BM, S + C);
        }
#undef STEP
#undef PRE
    }
}

// ---------------------------------------------------------------------------
extern "C" void kernel_launch(void* const* d_in, const int* in_sizes, int n_in,
                              void* d_out, int out_size, void* d_ws, size_t ws_size,
                              hipStream_t stream)
{
    const float* delay_len = (const float*)d_in[0];
    const float* raw_gain  = (const float*)d_in[1];
    const float* raw_coeff = (const float*)d_in[2];
    const float* exc       = (const float*)d_in[3];
    const float* burst     = (const float*)d_in[4];
    float* ws  = (float*)d_ws;
    float* out = (float*)d_out;

    // zero the grid-barrier {cnt, gen} before every launch (ws is re-poisoned)
    hipMemsetAsync((char*)d_ws + WS_BAR, 0, 8, stream);
    hipLaunchKernelGGL(k_all, dim3(NBLOCKS), dim3(256), 0, stream,
                       delay_len, raw_gain, raw_coeff, exc, burst, ws, out);
}

// Round 15
// 233.407 us; speedup vs baseline: 1.5917x; 1.5917x over previous
//
#include <hip/hip_runtime.h>
#include <math.h>
#include <limits.h>

#define N_SAMPLES 65536
#define N_FRAMES  128
#define NUM_COEFF 6
#define NSEG      126        // N_FRAMES - 2
#define VEC_SIZE  808
#define ZCLAMP    (VEC_SIZE - 7)   // 801

// ---- workspace layout (byte offsets) ----
#define WS_XL    0           // float xl[65536]  (x with tile-initial state 0)
#define WS_PP    262144      // float PP[65536]  (in-tile prefix product of -a)
#define WS_VALS  524288      // float vals8[65536][8]; slot 7 = z (float)
#define WS_TM    2621440     // float TM[64] tile aggregate multiplier
#define WS_TC    2621696     // float TC[64] tile aggregate offset
#define WS_D     2621952     // int: min dependency distance of final system
#define WS_PL    2622464     // 3 SoA planes: float4[65536] each (24 bf16 coeffs)
#define WS_MQ    5768192     // float4[65536] = (X15, ring_idx_f, u12, u13)

// ---------------------------------------------------------------------------
// K1: front-end, 320 blocks (unchanged from R9 — verified).
// Blocks 0..255: spline -> vals8. Blocks 256..319: exc IIR phase-1 tiles.
// ---------------------------------------------------------------------------
__global__ __launch_bounds__(256) void k_front(
    const float* __restrict__ delay_len,
    const float* __restrict__ raw_gain,
    const float* __restrict__ raw_coeff,
    const float* __restrict__ exc,
    const float* __restrict__ burst,
    float* __restrict__ ws)
{
    const int tid = threadIdx.x;
    const int b = blockIdx.x;

    if (b >= 256) {
        float* xl = ws + WS_XL / 4;
        float* PP = ws + WS_PP / 4;
        float* TM = ws + WS_TM / 4;
        float* TC = ws + WS_TC / 4;
        const int tile = b - 256;
        const int base = tile * 1024 + tid * 4;

        if (tile == 0 && tid == 0) *(int*)((char*)ws + WS_D) = 0x7fffffff;

        const float4 a4 = *(const float4*)(exc + base);
        const float4 b4 = *(const float4*)(burst + base);

        float m = -a4.x,            c = b4.x;
        m = -a4.y * m;              c = b4.y - a4.y * c;
        m = -a4.z * m;              c = b4.z - a4.z * c;
        m = -a4.w * m;              c = b4.w - a4.w * c;

        __shared__ float sm[256], sc[256];
        sm[tid] = m; sc[tid] = c;
        __syncthreads();
        for (int off = 1; off < 256; off <<= 1) {
            const float cm = sm[tid], cc = sc[tid];
            float pm = 1.f, pc = 0.f;
            if (tid >= off) { pm = sm[tid - off]; pc = sc[tid - off]; }
            __syncthreads();
            if (tid >= off) { sm[tid] = cm * pm; sc[tid] = cm * pc + cc; }
            __syncthreads();
        }
        float y = (tid == 0) ? 0.f : sc[tid - 1];
        float P = (tid == 0) ? 1.f : sm[tid - 1];

        float4 x4, p4;
        y = b4.x - a4.x * y;  P = -a4.x * P;  x4.x = y; p4.x = P;
        y = b4.y - a4.y * y;  P = -a4.y * P;  x4.y = y; p4.y = P;
        y = b4.z - a4.z * y;  P = -a4.z * P;  x4.z = y; p4.z = P;
        y = b4.w - a4.w * y;  P = -a4.w * P;  x4.w = y; p4.w = P;

        *(float4*)(xl + base) = x4;
        *(float4*)(PP + base) = p4;
        if (tid == 255) { TM[tile] = sm[255]; TC[tile] = sc[255]; }
        return;
    }

    float* vals8 = ws + WS_VALS / 4;
    __shared__ float Y[7][N_FRAMES];
    __shared__ float M[7][N_FRAMES];
    __shared__ double cp[NSEG];
    __shared__ double dp[7][NSEG];

    if (tid < N_FRAMES) {
        float s[NUM_COEFF];
        float sum = 0.f;
        for (int j = 0; j < NUM_COEFF; ++j) {
            s[j] = 1.f / (1.f + expf(-raw_coeff[tid * NUM_COEFF + j]));
            sum += s[j];
        }
        const float gain = 1.f / (1.f + expf(-raw_gain[0]));
        for (int j = 0; j < NUM_COEFF; ++j)
            Y[1 + j][tid] = s[j] / sum * gain;
        Y[0][tid] = delay_len[tid];
    }
    __syncthreads();

    if (tid == 0) {
        cp[0] = 0.25;
        for (int i = 1; i < NSEG; ++i) cp[i] = 1.0 / (4.0 - cp[i - 1]);
    }
    __syncthreads();

    if (tid < 7) {
        const float* y = Y[tid];
        const double inv_h2 = 127.0 * 127.0;
        double prev = 6.0 * ((double)y[2] - 2.0 * (double)y[1] + (double)y[0]) * inv_h2 * 0.25;
        dp[tid][0] = prev;
        for (int i = 1; i < NSEG; ++i) {
            double ri = 6.0 * ((double)y[i + 2] - 2.0 * (double)y[i + 1] + (double)y[i]) * inv_h2;
            prev = (ri - prev) * cp[i];
            dp[tid][i] = prev;
        }
        float* Mc = M[tid];
        Mc[0] = 0.f; Mc[N_FRAMES - 1] = 0.f;
        double mi = dp[tid][NSEG - 1];
        Mc[NSEG] = (float)mi;
        for (int i = NSEG - 2; i >= 0; --i) {
            mi = dp[tid][i] - cp[i] * mi;
            Mc[i + 1] = (float)mi;
        }
    }
    __syncthreads();

    const int t = b * 256 + tid;
    const float h = 1.0f / 127.0f;
    const float tf = (float)t * (1.0f / 65535.0f);
    int idx = (int)floorf(tf * 127.0f);
    idx = min(max(idx, 0), 126);
    const float s = tf - (float)idx * h;
    const float s2 = s * s;
    const float s3 = s2 * s;

    float o[7];
#pragma unroll
    for (int c = 0; c < 7; ++c) {
        const float yi  = Y[c][idx];
        const float yi1 = Y[c][idx + 1];
        const float Mi  = M[c][idx];
        const float Mi1 = M[c][idx + 1];
        const float bb = (yi1 - yi) / h - h * (2.f * Mi + Mi1) / 6.f;
        o[c] = yi + bb * s + 0.5f * Mi * s2 + (Mi1 - Mi) * s3 / (6.f * h);
    }
    const float delay = o[0];
    int z = (int)floorf(delay);
    const float alfa = delay - (float)z;
    z = min(max(z, 0), ZCLAMP);

    float v[8];
    v[0] = -((1.f - alfa) * o[1]);
#pragma unroll
    for (int j = 1; j <= 5; ++j)
        v[j] = -(alfa * o[j] + (1.f - alfa) * o[j + 1]);
    v[6] = -(alfa * o[6]);
    v[7] = (float)z;

    float4* vp = (float4*)(vals8 + (size_t)t * 8);
    vp[0] = make_float4(v[0], v[1], v[2], v[3]);
    vp[1] = make_float4(v[4], v[5], v[6], v[7]);
}

// bf16 RNE pack helpers
__device__ __forceinline__ unsigned int bf16_hi(float f) {
    unsigned int b = __float_as_uint(f);
    b = b + 0x7fffu + ((b >> 16) & 1u);
    return b & 0xffff0000u;
}
__device__ __forceinline__ unsigned int bf16_lo(float f) {
    unsigned int b = __float_as_uint(f);
    b = b + 0x7fffu + ((b >> 16) & 1u);
    return b >> 16;
}

// ---------------------------------------------------------------------------
// K2: fused L1 + L1.5 expansion (parallel, 256 blocks) — unchanged from R11
// (64-B rows verified: absmax identical to the 72/80-B f32 versions).
// ---------------------------------------------------------------------------
__global__ __launch_bounds__(256) void k_exp(float* __restrict__ ws)
{
    __shared__ float accL[256 * 33];
    __shared__ float xwin[1920];
    __shared__ float yin[64];
    __shared__ int dmin;
    const int tid = threadIdx.x;
    const int T0 = blockIdx.x * 256;
    const int t = T0 + tid;
    const int wlo = T0 - 1664;

    const float* xl = ws + WS_XL / 4;
    const float* PP = ws + WS_PP / 4;
    const float* vals8 = ws + WS_VALS / 4;
    const float* TM = ws + WS_TM / 4;
    const float* TC = ws + WS_TC / 4;
    float4* PL = (float4*)((char*)ws + WS_PL);
    float4* MQ = (float4*)((char*)ws + WS_MQ);
    int* D = (int*)((char*)ws + WS_D);

    float* acc = accL + tid * 33;
#pragma unroll
    for (int o = 0; o < 32; ++o) acc[o] = 0.f;

    if (tid == 0) {
        dmin = 0x7fffffff;
        float y = 0.f;
        for (int k = 0; k < 64; ++k) {
            yin[k] = y;
            y = TC[k] + TM[k] * y;
        }
    }
    __syncthreads();

    for (int i = tid; i < 1920; i += 256) {
        const int p = wlo + i;
        float xv = 0.f;
        if (p >= 0 && p < N_SAMPLES)
            xv = xl[p] + PP[p] * yin[p >> 10];
        xwin[i] = xv;
    }
    __syncthreads();

#define XREAD(p) xwin[(p) - wlo]

    const float4* vp = (const float4*)(vals8 + (size_t)t * 8);
    const float4 r0 = vp[0], r1 = vp[1];
    const float vj[7] = {r0.x, r0.y, r0.z, r0.w, r1.x, r1.y, r1.z};
    const int m0 = t - 1 - (int)r1.w;
    float X1 = XREAD(t);

    float4 s0[7], s1[7];
    float xs[7];
    int sm0[7];
    bool val[7];
    int pmin = INT_MAX;
#pragma unroll
    for (int j = 0; j < 7; ++j) {
        const int s = m0 - j;
        val[j] = (s >= 0);
        const int si = val[j] ? s : 0;
        const float4* sp = (const float4*)(vals8 + (size_t)si * 8);
        s0[j] = sp[0]; s1[j] = sp[1];
        xs[j] = XREAD(val[j] ? s : t);
        sm0[j] = s - 1 - (int)s1[j].w;
        if (val[j]) pmin = min(pmin, sm0[j]);
    }
    if (pmin == INT_MAX) pmin = t - 900;
    const int B1 = (pmin - 6) & ~3;

#pragma unroll
    for (int j = 0; j < 7; ++j) {
        if (!val[j]) continue;
        X1 -= vj[j] * xs[j];
        const float sv[7] = {s0[j].x, s0[j].y, s0[j].z, s0[j].w,
                             s1[j].x, s1[j].y, s1[j].z};
        const int ob = sm0[j] - B1;
#pragma unroll
        for (int k = 0; k < 7; ++k) {
            int o = ob - k;
            o = min(max(o, 0), 31);
            acc[o] += vj[j] * sv[k];
        }
    }

    float c1f[32];
#pragma unroll
    for (int o = 0; o < 32; ++o) { c1f[o] = acc[o]; acc[o] = 0.f; }

    float X15 = X1;
    int first = -1;
#pragma unroll
    for (int o = 0; o < 32; ++o)
        if (first < 0 && c1f[o] != 0.f && (B1 + o) >= 0) first = o;

    int B2 = 0, maxq = INT_MIN;
    if (first >= 0) {
        const int pf = B1 + first;
        const float zf = ((const float4*)(vals8 + (size_t)pf * 8))[1].w;
        B2 = ((pf - 1 - (int)zf) - 6) & ~3;

#pragma unroll
        for (int o = 0; o < 32; ++o) {
            const float co = c1f[o];
            const int p = B1 + o;
            if (co == 0.f || p < 0) continue;
            const float4* pv = (const float4*)(vals8 + (size_t)p * 8);
            const float4 v0 = pv[0], v1 = pv[1];
            X15 += co * XREAD(p);
            const int rp = p - 1 - (int)v1.w;
            maxq = max(maxq, rp);
            const float sv[7] = {v0.x, v0.y, v0.z, v0.w, v1.x, v1.y, v1.z};
            const int ob = rp - B2;
#pragma unroll
            for (int j = 0; j < 7; ++j) {
                int oo = ob - j;
                oo = min(max(oo, 0), 27);   // band fits in [0,27]
                acc[oo] -= co * sv[j];
            }
        }
    }
#undef XREAD

    unsigned int u[14];
#pragma unroll
    for (int i = 0; i < 14; ++i)
        u[i] = bf16_hi(acc[2 * i]) | bf16_lo(acc[2 * i + 1]);

    PL[t]             = make_float4(__uint_as_float(u[0]),  __uint_as_float(u[1]),
                                    __uint_as_float(u[2]),  __uint_as_float(u[3]));
    PL[t + 65536]     = make_float4(__uint_as_float(u[4]),  __uint_as_float(u[5]),
                                    __uint_as_float(u[6]),  __uint_as_float(u[7]));
    PL[t + 2 * 65536] = make_float4(__uint_as_float(u[8]),  __uint_as_float(u[9]),
                                    __uint_as_float(u[10]), __uint_as_float(u[11]));
    MQ[t] = make_float4(X15, (float)(B2 & 2047),
                        __uint_as_float(u[12]), __uint_as_float(u[13]));

    if (first >= 0 && maxq > INT_MIN) atomicMin(&dmin, t - maxq);
    __syncthreads();
    if (tid == 0) atomicMin(D, dmin);
}

// lgkm-only workgroup barrier (global loads/stores stay in flight)
__device__ __forceinline__ void bar_lgkm() {
    asm volatile("s_waitcnt lgkmcnt(0)\n\ts_barrier" ::: "memory");
}

// ---------------------------------------------------------------------------
// K3: sequential chunked recurrence — R12's verified fast skeleton
// (134.8 µs: 4 waves, 2 samples/lane, depth-2 prefetch, lgkm barrier,
// UNCONDITIONAL clamped loads, full double-written ring, 64-B rows) with
// one change: H-half prefetch uses COMPACT indexing tH = BASE+256+(tid&63).
// Lanes 0..C-257 (<=63) get exactly their row; all other lanes load 64-row
// duplicates served from hot L1 lines. Distinct H-rows/step: 256 -> 64
// (total stream 512 -> 320 rows, -38%) with loads still unconditional and
// uniform — avoiding R11's exec-masked-load vmcnt-drain trap. Requires
// C <= 320 (D ~ 303 ✓; clamp added).
// ---------------------------------------------------------------------------
__global__ __launch_bounds__(256, 1) void k_ks3(
    const float* __restrict__ ws_c,
    float* __restrict__ out)
{
    __shared__ __align__(16) float ring2[4096];
    const int tid = threadIdx.x;
    const float4* PL = (const float4*)((const char*)ws_c + WS_PL);
    const float4* MQ = (const float4*)((const char*)ws_c + WS_MQ);
    const int* Dp = (const int*)((const char*)ws_c + WS_D);

    for (int i = tid; i < 4096; i += 256) ring2[i] = 0.f;
    __syncthreads();

    int C = *Dp;
    if (C > 320) C = 320;   // H-half covers at most 64 rows (compact index)
    if (C < 1) C = 1;
    const int C2 = 2 * C;
    const int hlane = tid & 63;   // compact H-row index

#define PRE(P0L, P1L, P2L, PML, P0H, P1H, P2H, PMH, BASE)                      \
    do {                                                                       \
        int tL = (BASE) + tid;        if (tL > N_SAMPLES - 1) tL = N_SAMPLES - 1; \
        P0L = PL[tL];  P1L = PL[tL + 65536];  P2L = PL[tL + 2 * 65536];        \
        PML = MQ[tL];                                                          \
        int tH = (BASE) + 256 + hlane; if (tH > N_SAMPLES - 1) tH = N_SAMPLES - 1; \
        P0H = PL[tH];  P1H = PL[tH + 65536];  P2H = PL[tH + 2 * 65536];        \
        PMH = MQ[tH];                                                          \
    } while (0)

#define DOT(P0, P1, P2, PM, YOUT)                                              \
    do {                                                                       \
        const int idx_ = (int)(PM).y;                                          \
        const unsigned int hi_ = 0xffff0000u;                                  \
        const unsigned int u_[14] = {                                          \
            __float_as_uint((P0).x), __float_as_uint((P0).y),                  \
            __float_as_uint((P0).z), __float_as_uint((P0).w),                  \
            __float_as_uint((P1).x), __float_as_uint((P1).y),                  \
            __float_as_uint((P1).z), __float_as_uint((P1).w),                  \
            __float_as_uint((P2).x), __float_as_uint((P2).y),                  \
            __float_as_uint((P2).z), __float_as_uint((P2).w),                  \
            __float_as_uint((PM).z), __float_as_uint((PM).w)};                 \
        float p0 = 0.f, p1 = 0.f, p2 = 0.f, p3 = 0.f;                          \
        _Pragma("unroll")                                                      \
        for (int q = 0; q < 7; ++q) {                                          \
            const float4 rv_ = *(const float4*)&ring2[idx_ + 4 * q];           \
            const unsigned int ua_ = u_[2 * q], ub_ = u_[2 * q + 1];           \
            p0 = fmaf(__uint_as_float(ua_ & hi_), rv_.x, p0);                  \
            p1 = fmaf(__uint_as_float(ua_ << 16), rv_.y, p1);                  \
            p2 = fmaf(__uint_as_float(ub_ & hi_), rv_.z, p2);                  \
            p3 = fmaf(__uint_as_float(ub_ << 16), rv_.w, p3);                  \
        }                                                                      \
        YOUT = (PM).x + ((p0 + p1) + (p2 + p3));                               \
    } while (0)

#define STEP(P0L, P1L, P2L, PML, P0H, P1H, P2H, PMH, S_)                       \
    do {                                                                       \
        const int t0 = (S_) + tid;                                             \
        if (tid < C && t0 < N_SAMPLES) {                                       \
            float y0; DOT(P0L, P1L, P2L, PML, y0);                             \
            const int w = t0 & 2047;                                           \
            ring2[w] = y0; ring2[w + 2048] = y0; out[t0] = y0;                 \
        }                                                                      \
        /* H sample: lane tid handles t = S+256+hlane; only valid (and   */    \
        /* stored) when tid < 64 so hlane == tid and 256+tid < C.        */    \
        const int t1 = (S_) + 256 + hlane;                                     \
        if (tid < 64 && 256 + tid < C && t1 < N_SAMPLES) {                     \
            float y1; DOT(P0H, P1H, P2H, PMH, y1);                             \
            const int w = t1 & 2047;                                           \
            ring2[w] = y1; ring2[w + 2048] = y1; out[t1] = y1;                 \
        }                                                                      \
        PRE(P0L, P1L, P2L, PML, P0H, P1H, P2H, PMH, (S_) + C2);                \
        bar_lgkm();                                                            \
    } while (0)

    float4 A0L, A1L, A2L, AML, A0H, A1H, A2H, AMH;
    float4 B0L, B1L, B2L, BML, B0H, B1H, B2H, BMH;

    PRE(A0L, A1L, A2L, AML, A0H, A1H, A2H, AMH, 0);
    PRE(B0L, B1L, B2L, BML, B0H, B1H, B2H, BMH, C);
    for (int S = 0; S < N_SAMPLES; S += C2) {
        STEP(A0L, A1L, A2L, AML, A0H, A1H, A2H, AMH, S);
        STEP(B0L, B1L, B2L, BML, B0H, B1H, B2H, BMH, S + C);
    }
#undef STEP
#undef DOT
#undef PRE
}

// ---------------------------------------------------------------------------
extern "C" void kernel_launch(void* const* d_in, const int* in_sizes, int n_in,
                              void* d_out, int out_size, void* d_ws, size_t ws_size,
                              hipStream_t stream)
{
    const float* delay_len = (const float*)d_in[0];
    const float* raw_gain  = (const float*)d_in[1];
    const float* raw_coeff = (const float*)d_in[2];
    const float* exc       = (const float*)d_in[3];
    const float* burst     = (const float*)d_in[4];
    float* ws  = (float*)d_ws;
    float* out = (float*)d_out;

    hipLaunchKernelGGL(k_front, dim3(320), dim3(256), 0, stream,
                       delay_len, raw_gain, raw_coeff, exc, burst, ws);
    hipLaunchKernelGGL(k_exp, dim3(256), dim3(256), 0, stream, ws);
    hipLaunchKernelGGL(k_ks3, dim3(1), dim3(256), 0, stream, ws, out);
}